// Round 14
// baseline (177.409 us; speedup 1.0000x reference)
//
#include <hip/hip_runtime.h>
#include <math.h>
#include <stdint.h>

#define H 768
#define S 256
#define NB 4      // batch
#define TOPK 4
#define L 4
#define NH 4      // biaffine h-split chunks (192 h each)

// 2/ln2: tanh(x) = 1 - 2/(2^(C*x)+1)
#define CSCALE 2.8853900817779268f

#define AGROUPS 98304   // 1024*768/8
#define BGROUPS 147456  // 1536*768/8

typedef __bf16 bf16x8 __attribute__((ext_vector_type(8)));
typedef __bf16 bf16x4 __attribute__((ext_vector_type(4)));
typedef float floatx4 __attribute__((ext_vector_type(4)));
typedef float floatx2 __attribute__((ext_vector_type(2)));

__device__ __forceinline__ float exp2_native(float x) {
#if __has_builtin(__builtin_amdgcn_exp2f)
  return __builtin_amdgcn_exp2f(x);
#else
  float r; asm("v_exp_f32 %0, %1" : "=v"(r) : "v"(x)); return r;
#endif
}
__device__ __forceinline__ float rcp_native(float x) {
#if __has_builtin(__builtin_amdgcn_rcpf)
  return __builtin_amdgcn_rcpf(x);
#else
  float r; asm("v_rcp_f32 %0, %1" : "=v"(r) : "v"(x)); return r;
#endif
}
// clamp to +-126 so Ei*Ej cannot produce inf*0=NaN; rcp(inf)=0 and rcp(1)=1
// give the correct tanh saturation at the extremes. (r3-r13 numerics, passed.)
__device__ __forceinline__ float exp2c(float x) {
  return exp2_native(fminf(126.f, fmaxf(-126.f, x)));
}
__device__ __forceinline__ floatx2 fma2(floatx2 a, floatx2 b, floatx2 c) {
#if __has_builtin(__builtin_elementwise_fma)
  return __builtin_elementwise_fma(a, b, c);
#else
  floatx2 r; r.x = fmaf(a.x, b.x, c.x); r.y = fmaf(a.y, b.y, c.y); return r;
#endif
}
__device__ __forceinline__ float fast_tanh(float x) {
  float cx = fminf(15.f, fmaxf(-15.f, x));
  float e = __expf(cx + cx);
  return __fdividef(e - 1.f, e + 1.f);
}
// async global->LDS, 16 B per lane. LDS dest = wave-uniform base + lane*16
// (m104); global src is per-lane.
__device__ __forceinline__ void gload16(const __bf16* g, __bf16* l) {
  __builtin_amdgcn_global_load_lds(
      (const __attribute__((address_space(1))) uint32_t*)g,
      (__attribute__((address_space(3))) uint32_t*)l, 16, 0, 0);
}

// ---------------------------------------------------------------------------
// Stage 0: one-shot fp32 -> bf16 hi/lo conversion of A (pooled) and the fused
// B matrix (Wa|Ua rows hi+lo; dense rows hi only). Rounding identical to the
// old in-GEMM conversion (RNE hi, then lo = f - hi) -> GEMM bit-identical.
__global__ __launch_bounds__(256) void tobf16(
    const float* __restrict__ pooled, const float* __restrict__ Wa_w,
    const float* __restrict__ Ua_w, const float* __restrict__ dense_w,
    __bf16* __restrict__ Ah, __bf16* __restrict__ Al,
    __bf16* __restrict__ Bh, __bf16* __restrict__ Bl,
    __bf16* __restrict__ Dh) {
  const int g = blockIdx.x * 256 + threadIdx.x;  // one bf16x8 group
  const float* src;
  __bf16* dh;
  __bf16* dl;
  if (g < AGROUPS) {
    src = pooled + (size_t)g * 8;
    dh = Ah + (size_t)g * 8;
    dl = Al + (size_t)g * 8;
  } else if (g < AGROUPS + BGROUPS) {
    const int q = g - AGROUPS;
    const int n = q / 96;               // fused proj column 0..1535
    const int k8 = (q - n * 96) * 8;
    src = ((n < H) ? Wa_w + (size_t)n * H : Ua_w + (size_t)(n - H) * H) + k8;
    dh = Bh + (size_t)q * 8;
    dl = Bl + (size_t)q * 8;
  } else {
    const int q = g - (AGROUPS + BGROUPS);
    const int d = q / 96;               // dense fused column 0..1535
    const int k8 = (q - d * 96) * 8;
    src = dense_w + ((d < H) ? ((size_t)d * (2 * H) + k8)
                             : ((size_t)(d - H) * (2 * H) + H + k8));
    dh = Dh + (size_t)q * 8;
    dl = nullptr;
  }
  float4 f0 = *(const float4*)src;
  float4 f1 = *(const float4*)(src + 4);
  float f[8] = {f0.x, f0.y, f0.z, f0.w, f1.x, f1.y, f1.z, f1.w};
  bf16x8 hv, lv;
#pragma unroll
  for (int k = 0; k < 8; ++k) {
    hv[k] = (__bf16)f[k];
    lv[k] = (__bf16)(f[k] - (float)hv[k]);
  }
  *(bf16x8*)dh = hv;
  if (dl) *(bf16x8*)dl = lv;
}

// ---------------------------------------------------------------------------
// Stage 1 (single GEMM, 64x64 tiles, r9 gload_lds staging): C = pooled @ B^T
// from pre-split bf16. Epilogue proj branch stores Ei = 2^(CSCALE*(c+bias))
// (clamped). Cols 1536..2303 = dense dep (+dense_b -> dpb); 2304..3071 = head.
__global__ __launch_bounds__(256) void mega_mfma(
    const __bf16* __restrict__ Ah, const __bf16* __restrict__ Al,
    const __bf16* __restrict__ Bh, const __bf16* __restrict__ Bl,
    const __bf16* __restrict__ Dh,
    const float* __restrict__ Wa_b, const float* __restrict__ Ua_b,
    const float* __restrict__ dense_b, float* __restrict__ hijT,
    __bf16* __restrict__ dpb, __bf16* __restrict__ hpb) {
  __shared__ __align__(16) __bf16 Ahs[2][64][32];
  __shared__ __align__(16) __bf16 Als[2][64][32];
  __shared__ __align__(16) __bf16 Bhs[2][64][32];
  __shared__ __align__(16) __bf16 Bls[2][64][32];   // 32 KB total
  const int m0 = blockIdx.x * 64;
  const int g = blockIdx.y;                  // swizzle: even->proj, odd->dense
  const int ng = (g & 1) ? (24 + (g >> 1)) : (g >> 1);   // 0..47
  const int n0 = ng * 64;
  const bool isproj = (ng < 24);
  const int t = threadIdx.x;
  const int arow = t >> 2;                   // tile row this thread feeds
  const int gsw = ((t & 3) ^ ((t >> 3) & 3)) * 8;  // swizzled src col (elems)
  const int ncol = n0 + arow;
  const __bf16* Asrh = Ah + (size_t)(m0 + arow) * H + gsw;
  const __bf16* Asrl = Al + (size_t)(m0 + arow) * H + gsw;
  const __bf16* Bsrh;
  const __bf16* Bsrl = nullptr;
  if (isproj) {
    Bsrh = Bh + (size_t)ncol * H + gsw;
    Bsrl = Bl + (size_t)ncol * H + gsw;
  } else {
    Bsrh = Dh + (size_t)(ncol - 2 * H) * H + gsw;
  }
  const int lane = t & 63;
  const int wave = t >> 6;
  const int w16 = wave * 16;                 // wave-uniform LDS row base
  const int wm = (wave & 1) * 32;
  const int wn = (wave >> 1) * 32;
  const int fm = lane & 15;
  const int quad = lane >> 4;
  const int fsw = (quad ^ ((fm >> 1) & 3)) * 8;  // swizzled read col (elems)
  floatx4 acc[2][2] = {};

  // prologue: stage K-step 0 into buf 0
  gload16(Asrh, &Ahs[0][w16][0]);
  gload16(Bsrh, &Bhs[0][w16][0]);
  if (isproj) {
    gload16(Asrl, &Als[0][w16][0]);
    gload16(Bsrl, &Bls[0][w16][0]);
  }

  for (int kc = 0; kc < H; kc += 32) {
    const int cur = (kc >> 5) & 1;
    __syncthreads();            // vmcnt(0)+barrier: buf[cur] ready for all
    if (kc + 32 < H) {          // prefetch next K-step into the other buffer
      const int nxt = cur ^ 1;
      gload16(Asrh + kc + 32, &Ahs[nxt][w16][0]);
      gload16(Bsrh + kc + 32, &Bhs[nxt][w16][0]);
      if (isproj) {
        gload16(Asrl + kc + 32, &Als[nxt][w16][0]);
        gload16(Bsrl + kc + 32, &Bls[nxt][w16][0]);
      }
    }
    bf16x8 afh[2], bfh[2];
#pragma unroll
    for (int i = 0; i < 2; ++i) {
      afh[i] = *(const bf16x8*)&Ahs[cur][wm + i * 16 + fm][fsw];
      bfh[i] = *(const bf16x8*)&Bhs[cur][wn + i * 16 + fm][fsw];
    }
    if (isproj) {
      bf16x8 afl[2], bfl[2];
#pragma unroll
      for (int i = 0; i < 2; ++i) {
        afl[i] = *(const bf16x8*)&Als[cur][wm + i * 16 + fm][fsw];
        bfl[i] = *(const bf16x8*)&Bls[cur][wn + i * 16 + fm][fsw];
      }
#pragma unroll
      for (int i = 0; i < 2; ++i)
#pragma unroll
        for (int j = 0; j < 2; ++j) {  // per-acc order hh,hl,lh == r7-r13
          acc[i][j] = __builtin_amdgcn_mfma_f32_16x16x32_bf16(afh[i], bfh[j], acc[i][j], 0, 0, 0);
          acc[i][j] = __builtin_amdgcn_mfma_f32_16x16x32_bf16(afh[i], bfl[j], acc[i][j], 0, 0, 0);
          acc[i][j] = __builtin_amdgcn_mfma_f32_16x16x32_bf16(afl[i], bfh[j], acc[i][j], 0, 0, 0);
        }
    } else {
#pragma unroll
      for (int i = 0; i < 2; ++i)
#pragma unroll
        for (int j = 0; j < 2; ++j)
          acc[i][j] = __builtin_amdgcn_mfma_f32_16x16x32_bf16(afh[i], bfh[j], acc[i][j], 0, 0, 0);
    }
  }
#pragma unroll
  for (int j = 0; j < 2; ++j) {
    const int col = n0 + wn + j * 16 + fm;
    if (col < 2 * H) {          // hijT[col][row] = 2^(scaled), float4 / 4 rows
      const float bias = (col < H) ? Wa_b[col] : Ua_b[col - H];
#pragma unroll
      for (int i = 0; i < 2; ++i) {
        float4 o;
        o.x = exp2c(CSCALE * (acc[i][j][0] + bias));
        o.y = exp2c(CSCALE * (acc[i][j][1] + bias));
        o.z = exp2c(CSCALE * (acc[i][j][2] + bias));
        o.w = exp2c(CSCALE * (acc[i][j][3] + bias));
        *(float4*)&hijT[(size_t)col * 1024 + m0 + wm + i * 16 + quad * 4] = o;
      }
    } else if (col < 3 * H) {   // dp: + dense_b, bf16
      const int o = col - 2 * H;
      const float bias = dense_b[o];
#pragma unroll
      for (int i = 0; i < 2; ++i)
#pragma unroll
        for (int rg = 0; rg < 4; ++rg) {
          const int row = m0 + wm + i * 16 + quad * 4 + rg;
          dpb[(size_t)row * H + o] = (__bf16)(acc[i][j][rg] + bias);
        }
    } else {                    // hp: raw, bf16
      const int o = col - 3 * H;
#pragma unroll
      for (int i = 0; i < 2; ++i)
#pragma unroll
        for (int rg = 0; rg < 4; ++rg) {
          const int row = m0 + wm + i * 16 + quad * 4 + rg;
          hpb[(size_t)row * H + o] = (__bf16)acc[i][j][rg];
        }
    }
  }
}

// ---------------------------------------------------------------------------
// Stage 2, r14: NO LDS staging -- hijT is 6 MB (L2-resident, 32 MB agg) and
// per-block unique traffic is ~38 MB total via L1/L2, so staging + 24
// barriers/block were pure overhead (guide common-mistake #7: attn V-staging
// drop was +26%). Each thread reads Ei (float2, coalesced 128B per 16-lane
// group) and Ej (float4, broadcast within 16-lane group) directly per h.
// Outer 24-iter loop pinned unroll-1 so <=1-2 iterations of loads are in
// flight (bounds the r3 hoist trap); inner 8-h fully unrolled, compile-time
// indices, named accumulators (rule #20). Same math, same h-ascending chain
// per output -> bit-identical to r13.
__global__ __launch_bounds__(256) void biaffine4(
    const float* __restrict__ hijT, const float* __restrict__ va,
    float* __restrict__ partials) {
  __shared__ __align__(16) float vas2[192];
  __shared__ float svas;
  const int z = blockIdx.z;
  const int b = z >> 2;
  const int ch = z & 3;
  const int hc0 = ch * 192;
  const int a0 = blockIdx.y * 64;
  const int c0 = blockIdx.x * 32;
  const int t = threadIdx.x;
  if (t < 192) vas2[t] = -2.f * va[hc0 + t];
  __syncthreads();
  if (t < 64) {
    float s = vas2[t] + vas2[t + 64] + vas2[t + 128];
#pragma unroll
    for (int off = 32; off > 0; off >>= 1) s += __shfl_xor(s, off);
    if (t == 0) svas = -0.5f * s;
  }
  __syncthreads();             // svas visible to all (loop has no barriers)
  const int ca = (t & 15) * 2;         // 2 c per thread
  const int aa = (t >> 4) * 4;         // 4 a per thread
  const float* bi = hijT + (size_t)hc0 * 1024 + b * S + c0 + ca;
  const float* bj = hijT + (size_t)(768 + hc0) * 1024 + b * S + a0 + aa;
  floatx2 acc0 = {0.f, 0.f}, acc1 = {0.f, 0.f};
  floatx2 acc2 = {0.f, 0.f}, acc3 = {0.f, 0.f};
  const floatx2 one = {1.f, 1.f};

#pragma unroll 1
  for (int hr = 0; hr < 192; hr += 8) {
    float vreg[8];
    *(float4*)&vreg[0] = *(const float4*)&vas2[hr + 0];
    *(float4*)&vreg[4] = *(const float4*)&vas2[hr + 4];
    const float* bih = bi + (size_t)hr * 1024;
    const float* bjh = bj + (size_t)hr * 1024;
#pragma unroll
    for (int h = 0; h < 8; ++h) {
      const float v = vreg[h];
      const floatx2 vv = {v, v};
      floatx2 Ei = *(const floatx2*)&bih[(size_t)h * 1024];
      float4  Ej = *(const float4*)&bjh[(size_t)h * 1024];
      floatx2 e0 = fma2(Ei, (floatx2){Ej.x, Ej.x}, one);
      floatx2 e1 = fma2(Ei, (floatx2){Ej.y, Ej.y}, one);
      floatx2 e2 = fma2(Ei, (floatx2){Ej.z, Ej.z}, one);
      floatx2 e3 = fma2(Ei, (floatx2){Ej.w, Ej.w}, one);
      floatx2 r0 = {rcp_native(e0.x), rcp_native(e0.y)};
      floatx2 r1 = {rcp_native(e1.x), rcp_native(e1.y)};
      floatx2 r2 = {rcp_native(e2.x), rcp_native(e2.y)};
      floatx2 r3 = {rcp_native(e3.x), rcp_native(e3.y)};
      acc0 = fma2(vv, r0, acc0);
      acc1 = fma2(vv, r1, acc1);
      acc2 = fma2(vv, r2, acc2);
      acc3 = fma2(vv, r3, acc3);
    }
  }
  const float sv = svas;
  float* pout = partials + (size_t)ch * (NB * S * S);
  float2 o0 = {acc0.x + sv, acc0.y + sv};
  float2 o1 = {acc1.x + sv, acc1.y + sv};
  float2 o2 = {acc2.x + sv, acc2.y + sv};
  float2 o3 = {acc3.x + sv, acc3.y + sv};
  *(float2*)&pout[(b * S + a0 + aa + 0) * S + c0 + ca] = o0;
  *(float2*)&pout[(b * S + a0 + aa + 1) * S + c0 + ca] = o1;
  *(float2*)&pout[(b * S + a0 + aa + 2) * S + c0 + ca] = o2;
  *(float2*)&pout[(b * S + a0 + aa + 3) * S + c0 + ca] = o3;
}

// ---------------------------------------------------------------------------
// Stage 3 (256 threads): combine of 4 partials parallel across all 4 waves;
// wave 0 re-reads the fp32 values from LDS (bit-exact) for top-4; each wave
// then computes one candidate's type logits.
__global__ __launch_bounds__(256) void topk_final(
    const float* __restrict__ partials, const __bf16* __restrict__ dpb,
    const __bf16* __restrict__ hpb, const float* __restrict__ fc_w,
    const float* __restrict__ fc_b, float* __restrict__ logits,
    float* __restrict__ out_type) {
  __shared__ int scand[TOPK];
  __shared__ float vsh[4][64];
  const int row = blockIdx.x;  // b*S + a
  const int t = threadIdx.x;
  const int wave = t >> 6, lane = t & 63;
  const int P = NB * S * S;
  {
    const int j = wave;
    const int c = row * S + j * 64 + lane;
    float s0 = partials[c]         + partials[c + P];
    float s1 = partials[c + 2 * P] + partials[c + 3 * P];
    float v = s0 + s1;
    logits[c] = v;
    vsh[j][lane] = v;
  }
  __syncthreads();
  if (wave == 0) {
    float v[4];
#pragma unroll
    for (int j = 0; j < 4; ++j) v[j] = vsh[j][lane];
#pragma unroll
    for (int k = 0; k < TOPK; ++k) {
      float bestv = v[0];
      int besti = lane;
#pragma unroll
      for (int j = 1; j < 4; ++j) {
        int c = j * 64 + lane;
        if (v[j] > bestv) { bestv = v[j]; besti = c; }
      }
#pragma unroll
      for (int off = 32; off > 0; off >>= 1) {
        float ov = __shfl_xor(bestv, off);
        int oi = __shfl_xor(besti, off);
        if (ov > bestv || (ov == bestv && oi < besti)) { bestv = ov; besti = oi; }
      }
      int mj = besti >> 6, ml = besti & 63;
#pragma unroll
      for (int j = 0; j < 4; ++j)
        if (lane == ml && j == mj) v[j] = -3.402823466e38f;
      if (lane == 0) scand[k] = besti;
    }
  }
  __syncthreads();
  const int k = wave;
  const __bf16* dp = dpb + (size_t)row * H;
  const int brow0 = (row >> 8) << 8;  // b*S
  const __bf16* hp = hpb + (size_t)(brow0 + scand[k]) * H;
  float acc[L] = {};
#pragma unroll
  for (int j = 0; j < 3; ++j) {
    const int o = j * 256 + lane * 4;
    bf16x4 dv = *(const bf16x4*)&dp[o];
    bf16x4 hv = *(const bf16x4*)&hp[o];
    float hd[4];
#pragma unroll
    for (int c = 0; c < 4; ++c)
      hd[c] = fast_tanh((float)dv[c] + (float)hv[c]);
#pragma unroll
    for (int l = 0; l < L; ++l) {
      float4 w = *(const float4*)&fc_w[l * H + o];
      acc[l] = fmaf(hd[0], w.x, acc[l]);
      acc[l] = fmaf(hd[1], w.y, acc[l]);
      acc[l] = fmaf(hd[2], w.z, acc[l]);
      acc[l] = fmaf(hd[3], w.w, acc[l]);
    }
  }
#pragma unroll
  for (int l = 0; l < L; ++l)
#pragma unroll
    for (int off = 32; off > 0; off >>= 1) acc[l] += __shfl_xor(acc[l], off);
  if (lane == 0) {
#pragma unroll
    for (int l = 0; l < L; ++l)
      out_type[((size_t)row * TOPK + k) * L + l] = acc[l] + fc_b[l];
  }
}

// ---------------------------------------------------------------------------
extern "C" void kernel_launch(void* const* d_in, const int* in_sizes, int n_in,
                              void* d_out, int out_size, void* d_ws, size_t ws_size,
                              hipStream_t stream) {
  const float* pooled  = (const float*)d_in[0];
  const float* Wa_w    = (const float*)d_in[1];
  const float* Wa_b    = (const float*)d_in[2];
  const float* Ua_w    = (const float*)d_in[3];
  const float* Ua_b    = (const float*)d_in[4];
  const float* va_w    = (const float*)d_in[5];
  const float* dense_w = (const float*)d_in[6];
  const float* dense_b = (const float*)d_in[7];
  const float* fc_w    = (const float*)d_in[8];
  const float* fc_b    = (const float*)d_in[9];

  float* logits   = (float*)d_out;            // (4,256,256)
  float* out_type = logits + NB * S * S;      // (4,256,4,4)

  // ws layout, ~23 MB. tobf16 writes Ah..Dh; mega reads them (gload_lds,
  // col-swizzled source), writes hijT (= exp2 of scaled proj) / dpb / hpb;
  // biaffine reads hijT directly (no LDS staging), writes partials (4
  // planes); topk reads partials/dpb/hpb.
  float*  hijT     = (float*)d_ws;                   // 1536 x 1024 f (6 MB)
  float*  partials = hijT + 1572864;                 // 1048576 f (4 MB)
  __bf16* dpb      = (__bf16*)(partials + 1048576);  // 786432 bf16
  __bf16* hpb      = dpb + 786432;                   // 786432 bf16
  __bf16* Ah       = hpb + 786432;                   // 786432 bf16 (1.5 MB)
  __bf16* Al       = Ah + 786432;                    // 786432 bf16
  __bf16* Bh       = Al + 786432;                    // 1179648 bf16 (2.25 MB)
  __bf16* Bl       = Bh + 1179648;                   // 1179648 bf16
  __bf16* Dh       = Bl + 1179648;                   // 1179648 bf16

  tobf16<<<dim3(1536), 256, 0, stream>>>(pooled, Wa_w, Ua_w, dense_w,
                                         Ah, Al, Bh, Bl, Dh);
  mega_mfma<<<dim3(16, 48), 256, 0, stream>>>(Ah, Al, Bh, Bl, Dh,
                                              Wa_b, Ua_b, dense_b,
                                              hijT, dpb, hpb);
  biaffine4<<<dim3(8, 4, NB * NH), 256, 0, stream>>>(hijT, va_w, partials);
  topk_final<<<dim3(1024), 256, 0, stream>>>(partials, dpb, hpb, fc_w, fc_b,
                                             logits, out_type);
}

// Round 15
// 134.687 us; speedup vs baseline: 1.3172x; 1.3172x over previous
//
#include <hip/hip_runtime.h>
#include <math.h>
#include <stdint.h>

#define H 768
#define S 256
#define NB 4      // batch
#define TOPK 4
#define L 4
#define NH 8      // biaffine h-split chunks (96 h each)

// 2/ln2: tanh(x) = 1 - 2/(2^(C*x)+1)
#define CSCALE 2.8853900817779268f

#define AGROUPS 98304   // 1024*768/8
#define BGROUPS 147456  // 1536*768/8

typedef __bf16 bf16x8 __attribute__((ext_vector_type(8)));
typedef __bf16 bf16x4 __attribute__((ext_vector_type(4)));
typedef float floatx4 __attribute__((ext_vector_type(4)));
typedef float floatx2 __attribute__((ext_vector_type(2)));

__device__ __forceinline__ float exp2_native(float x) {
#if __has_builtin(__builtin_amdgcn_exp2f)
  return __builtin_amdgcn_exp2f(x);
#else
  float r; asm("v_exp_f32 %0, %1" : "=v"(r) : "v"(x)); return r;
#endif
}
__device__ __forceinline__ float rcp_native(float x) {
#if __has_builtin(__builtin_amdgcn_rcpf)
  return __builtin_amdgcn_rcpf(x);
#else
  float r; asm("v_rcp_f32 %0, %1" : "=v"(r) : "v"(x)); return r;
#endif
}
// clamp to +-126 so Ei*Ej cannot produce inf*0=NaN; rcp(inf)=0 and rcp(1)=1
// give the correct tanh saturation at the extremes. (r3-r13 numerics, passed.)
__device__ __forceinline__ float exp2c(float x) {
  return exp2_native(fminf(126.f, fmaxf(-126.f, x)));
}
__device__ __forceinline__ floatx2 fma2(floatx2 a, floatx2 b, floatx2 c) {
#if __has_builtin(__builtin_elementwise_fma)
  return __builtin_elementwise_fma(a, b, c);
#else
  floatx2 r; r.x = fmaf(a.x, b.x, c.x); r.y = fmaf(a.y, b.y, c.y); return r;
#endif
}
__device__ __forceinline__ float fast_tanh(float x) {
  float cx = fminf(15.f, fmaxf(-15.f, x));
  float e = __expf(cx + cx);
  return __fdividef(e - 1.f, e + 1.f);
}
// async global->LDS, 16 B per lane. LDS dest = wave-uniform base + lane*16
// (m104); global src is per-lane.
__device__ __forceinline__ void gload16(const __bf16* g, __bf16* l) {
  __builtin_amdgcn_global_load_lds(
      (const __attribute__((address_space(1))) uint32_t*)g,
      (__attribute__((address_space(3))) uint32_t*)l, 16, 0, 0);
}

// ---------------------------------------------------------------------------
// Stage 0: one-shot fp32 -> bf16 hi/lo conversion of A (pooled) and the fused
// B matrix (Wa|Ua rows hi+lo; dense rows hi only). Rounding identical to the
// old in-GEMM conversion (RNE hi, then lo = f - hi) -> GEMM bit-identical.
__global__ __launch_bounds__(256) void tobf16(
    const float* __restrict__ pooled, const float* __restrict__ Wa_w,
    const float* __restrict__ Ua_w, const float* __restrict__ dense_w,
    __bf16* __restrict__ Ah, __bf16* __restrict__ Al,
    __bf16* __restrict__ Bh, __bf16* __restrict__ Bl,
    __bf16* __restrict__ Dh) {
  const int g = blockIdx.x * 256 + threadIdx.x;  // one bf16x8 group
  const float* src;
  __bf16* dh;
  __bf16* dl;
  if (g < AGROUPS) {
    src = pooled + (size_t)g * 8;
    dh = Ah + (size_t)g * 8;
    dl = Al + (size_t)g * 8;
  } else if (g < AGROUPS + BGROUPS) {
    const int q = g - AGROUPS;
    const int n = q / 96;               // fused proj column 0..1535
    const int k8 = (q - n * 96) * 8;
    src = ((n < H) ? Wa_w + (size_t)n * H : Ua_w + (size_t)(n - H) * H) + k8;
    dh = Bh + (size_t)q * 8;
    dl = Bl + (size_t)q * 8;
  } else {
    const int q = g - (AGROUPS + BGROUPS);
    const int d = q / 96;               // dense fused column 0..1535
    const int k8 = (q - d * 96) * 8;
    src = dense_w + ((d < H) ? ((size_t)d * (2 * H) + k8)
                             : ((size_t)(d - H) * (2 * H) + H + k8));
    dh = Dh + (size_t)q * 8;
    dl = nullptr;
  }
  float4 f0 = *(const float4*)src;
  float4 f1 = *(const float4*)(src + 4);
  float f[8] = {f0.x, f0.y, f0.z, f0.w, f1.x, f1.y, f1.z, f1.w};
  bf16x8 hv, lv;
#pragma unroll
  for (int k = 0; k < 8; ++k) {
    hv[k] = (__bf16)f[k];
    lv[k] = (__bf16)(f[k] - (float)hv[k]);
  }
  *(bf16x8*)dh = hv;
  if (dl) *(bf16x8*)dl = lv;
}

// ---------------------------------------------------------------------------
// Stage 1 (single GEMM, 64x64 tiles, r9 gload_lds staging): C = pooled @ B^T
// from pre-split bf16. Epilogue proj branch stores Ei = 2^(CSCALE*(c+bias))
// (clamped). Cols 1536..2303 = dense dep (+dense_b -> dpb); 2304..3071 = head.
__global__ __launch_bounds__(256) void mega_mfma(
    const __bf16* __restrict__ Ah, const __bf16* __restrict__ Al,
    const __bf16* __restrict__ Bh, const __bf16* __restrict__ Bl,
    const __bf16* __restrict__ Dh,
    const float* __restrict__ Wa_b, const float* __restrict__ Ua_b,
    const float* __restrict__ dense_b, float* __restrict__ hijT,
    __bf16* __restrict__ dpb, __bf16* __restrict__ hpb) {
  __shared__ __align__(16) __bf16 Ahs[2][64][32];
  __shared__ __align__(16) __bf16 Als[2][64][32];
  __shared__ __align__(16) __bf16 Bhs[2][64][32];
  __shared__ __align__(16) __bf16 Bls[2][64][32];   // 32 KB total
  const int m0 = blockIdx.x * 64;
  const int g = blockIdx.y;                  // swizzle: even->proj, odd->dense
  const int ng = (g & 1) ? (24 + (g >> 1)) : (g >> 1);   // 0..47
  const int n0 = ng * 64;
  const bool isproj = (ng < 24);
  const int t = threadIdx.x;
  const int arow = t >> 2;                   // tile row this thread feeds
  const int gsw = ((t & 3) ^ ((t >> 3) & 3)) * 8;  // swizzled src col (elems)
  const int ncol = n0 + arow;
  const __bf16* Asrh = Ah + (size_t)(m0 + arow) * H + gsw;
  const __bf16* Asrl = Al + (size_t)(m0 + arow) * H + gsw;
  const __bf16* Bsrh;
  const __bf16* Bsrl = nullptr;
  if (isproj) {
    Bsrh = Bh + (size_t)ncol * H + gsw;
    Bsrl = Bl + (size_t)ncol * H + gsw;
  } else {
    Bsrh = Dh + (size_t)(ncol - 2 * H) * H + gsw;
  }
  const int lane = t & 63;
  const int wave = t >> 6;
  const int w16 = wave * 16;                 // wave-uniform LDS row base
  const int wm = (wave & 1) * 32;
  const int wn = (wave >> 1) * 32;
  const int fm = lane & 15;
  const int quad = lane >> 4;
  const int fsw = (quad ^ ((fm >> 1) & 3)) * 8;  // swizzled read col (elems)
  floatx4 acc[2][2] = {};

  // prologue: stage K-step 0 into buf 0
  gload16(Asrh, &Ahs[0][w16][0]);
  gload16(Bsrh, &Bhs[0][w16][0]);
  if (isproj) {
    gload16(Asrl, &Als[0][w16][0]);
    gload16(Bsrl, &Bls[0][w16][0]);
  }

  for (int kc = 0; kc < H; kc += 32) {
    const int cur = (kc >> 5) & 1;
    __syncthreads();            // vmcnt(0)+barrier: buf[cur] ready for all
    if (kc + 32 < H) {          // prefetch next K-step into the other buffer
      const int nxt = cur ^ 1;
      gload16(Asrh + kc + 32, &Ahs[nxt][w16][0]);
      gload16(Bsrh + kc + 32, &Bhs[nxt][w16][0]);
      if (isproj) {
        gload16(Asrl + kc + 32, &Als[nxt][w16][0]);
        gload16(Bsrl + kc + 32, &Bls[nxt][w16][0]);
      }
    }
    bf16x8 afh[2], bfh[2];
#pragma unroll
    for (int i = 0; i < 2; ++i) {
      afh[i] = *(const bf16x8*)&Ahs[cur][wm + i * 16 + fm][fsw];
      bfh[i] = *(const bf16x8*)&Bhs[cur][wn + i * 16 + fm][fsw];
    }
    if (isproj) {
      bf16x8 afl[2], bfl[2];
#pragma unroll
      for (int i = 0; i < 2; ++i) {
        afl[i] = *(const bf16x8*)&Als[cur][wm + i * 16 + fm][fsw];
        bfl[i] = *(const bf16x8*)&Bls[cur][wn + i * 16 + fm][fsw];
      }
#pragma unroll
      for (int i = 0; i < 2; ++i)
#pragma unroll
        for (int j = 0; j < 2; ++j) {  // per-acc order hh,hl,lh == r7-r13
          acc[i][j] = __builtin_amdgcn_mfma_f32_16x16x32_bf16(afh[i], bfh[j], acc[i][j], 0, 0, 0);
          acc[i][j] = __builtin_amdgcn_mfma_f32_16x16x32_bf16(afh[i], bfl[j], acc[i][j], 0, 0, 0);
          acc[i][j] = __builtin_amdgcn_mfma_f32_16x16x32_bf16(afl[i], bfh[j], acc[i][j], 0, 0, 0);
        }
    } else {
#pragma unroll
      for (int i = 0; i < 2; ++i)
#pragma unroll
        for (int j = 0; j < 2; ++j)
          acc[i][j] = __builtin_amdgcn_mfma_f32_16x16x32_bf16(afh[i], bfh[j], acc[i][j], 0, 0, 0);
    }
  }
#pragma unroll
  for (int j = 0; j < 2; ++j) {
    const int col = n0 + wn + j * 16 + fm;
    if (col < 2 * H) {          // hijT[col][row] = 2^(scaled), float4 / 4 rows
      const float bias = (col < H) ? Wa_b[col] : Ua_b[col - H];
#pragma unroll
      for (int i = 0; i < 2; ++i) {
        float4 o;
        o.x = exp2c(CSCALE * (acc[i][j][0] + bias));
        o.y = exp2c(CSCALE * (acc[i][j][1] + bias));
        o.z = exp2c(CSCALE * (acc[i][j][2] + bias));
        o.w = exp2c(CSCALE * (acc[i][j][3] + bias));
        *(float4*)&hijT[(size_t)col * 1024 + m0 + wm + i * 16 + quad * 4] = o;
      }
    } else if (col < 3 * H) {   // dp: + dense_b, bf16
      const int o = col - 2 * H;
      const float bias = dense_b[o];
#pragma unroll
      for (int i = 0; i < 2; ++i)
#pragma unroll
        for (int rg = 0; rg < 4; ++rg) {
          const int row = m0 + wm + i * 16 + quad * 4 + rg;
          dpb[(size_t)row * H + o] = (__bf16)(acc[i][j][rg] + bias);
        }
    } else {                    // hp: raw, bf16
      const int o = col - 3 * H;
#pragma unroll
      for (int i = 0; i < 2; ++i)
#pragma unroll
        for (int rg = 0; rg < 4; ++rg) {
          const int row = m0 + wm + i * 16 + quad * 4 + rg;
          hpb[(size_t)row * H + o] = (__bf16)acc[i][j][rg];
        }
    }
  }
}

// ---------------------------------------------------------------------------
// Stage 2 (r12 form, best measured 134.8us): exp-product with 64a x 64c tile,
// 16 outputs/thread (4a x 4c), grid 4x4x32 = 512 blocks. 8-h LDS-staged
// barrier windows are LOAD-BEARING (r14: removing them -> latency-bound
// 69.9us, VALUBusy 24%); they both hide L2 latency and bound the hoistable
// ds_read set. Full unroll = compile-time indices, named accs (rule #20).
__global__ __launch_bounds__(256) void biaffine4(
    const float* __restrict__ hijT, const float* __restrict__ va,
    float* __restrict__ partials) {
  __shared__ __align__(16) float his[2][8][66];   // c-side: 64 cols (+2 pad)
  __shared__ __align__(16) float hjs[2][8][66];   // a-side: 64 cols (+2 pad)
  __shared__ __align__(16) float vas2[96];
  __shared__ float svas;
  const int z = blockIdx.z;
  const int b = z >> 3;
  const int ch = z & 7;
  const int hc0 = ch * 96;
  const int a0 = blockIdx.y * 64;
  const int c0 = blockIdx.x * 64;
  const int t = threadIdx.x;
  if (t < 96) vas2[t] = -2.f * va[hc0 + t];
  __syncthreads();
  if (t < 64) {
    float s = vas2[t] + ((t < 32) ? vas2[t + 64] : 0.f);
#pragma unroll
    for (int off = 32; off > 0; off >>= 1) s += __shfl_xor(s, off);
    if (t == 0) svas = -0.5f * s;
  }
  const int lh = t >> 5;       // h-row 0..7 (slow)
  const int lr = t & 31;       // col (fast, coalesced)
  const int ca = (t & 15) * 4;         // 4 c per thread
  const int aa = (t >> 4) * 4;         // 4 a per thread
  const float* bi = hijT + (size_t)(hc0 + lh) * 1024 + b * S + c0 + lr;
  const float* bj = hijT + (size_t)(768 + hc0 + lh) * 1024 + b * S + a0 + lr;
  // acc[a-row r][c-pair p]: r in 0..3, p in 0..1 (c+0,c+1 | c+2,c+3)
  floatx2 a0l = {0.f, 0.f}, a0h = {0.f, 0.f};
  floatx2 a1l = {0.f, 0.f}, a1h = {0.f, 0.f};
  floatx2 a2l = {0.f, 0.f}, a2h = {0.f, 0.f};
  floatx2 a3l = {0.f, 0.f}, a3h = {0.f, 0.f};
  const floatx2 one = {1.f, 1.f};

  float pi0 = bi[0], pi1 = bi[32], pj0 = bj[0], pj1 = bj[32];
  for (int hr = 0; hr < 96; hr += 8) {
    const int bf = (hr >> 3) & 1;
    his[bf][lh][lr]      = pi0;
    his[bf][lh][lr + 32] = pi1;
    hjs[bf][lh][lr]      = pj0;
    hjs[bf][lh][lr + 32] = pj1;
    __syncthreads();
    if (hr + 8 < 96) {
      const size_t off = (size_t)(hr + 8) * 1024;
      pi0 = bi[off];
      pi1 = bi[off + 32];
      pj0 = bj[off];
      pj1 = bj[off + 32];
    }
    float vreg[8];
    *(float4*)&vreg[0] = *(const float4*)&vas2[hr + 0];
    *(float4*)&vreg[4] = *(const float4*)&vas2[hr + 4];
#pragma unroll
    for (int h = 0; h < 8; ++h) {
      const float v = vreg[h];
      const floatx2 vv = {v, v};
      floatx2 Eil = *(const floatx2*)&his[bf][h][ca];      // c+0, c+1
      floatx2 Eih = *(const floatx2*)&his[bf][h][ca + 2];  // c+2, c+3
      float4  Ej  = *(const float4*)&hjs[bf][h][aa];       // a+0..a+3
      floatx2 e0l = fma2(Eil, (floatx2){Ej.x, Ej.x}, one);
      floatx2 e0h = fma2(Eih, (floatx2){Ej.x, Ej.x}, one);
      floatx2 e1l = fma2(Eil, (floatx2){Ej.y, Ej.y}, one);
      floatx2 e1h = fma2(Eih, (floatx2){Ej.y, Ej.y}, one);
      floatx2 e2l = fma2(Eil, (floatx2){Ej.z, Ej.z}, one);
      floatx2 e2h = fma2(Eih, (floatx2){Ej.z, Ej.z}, one);
      floatx2 e3l = fma2(Eil, (floatx2){Ej.w, Ej.w}, one);
      floatx2 e3h = fma2(Eih, (floatx2){Ej.w, Ej.w}, one);
      floatx2 r0l = {rcp_native(e0l.x), rcp_native(e0l.y)};
      floatx2 r0h = {rcp_native(e0h.x), rcp_native(e0h.y)};
      floatx2 r1l = {rcp_native(e1l.x), rcp_native(e1l.y)};
      floatx2 r1h = {rcp_native(e1h.x), rcp_native(e1h.y)};
      floatx2 r2l = {rcp_native(e2l.x), rcp_native(e2l.y)};
      floatx2 r2h = {rcp_native(e2h.x), rcp_native(e2h.y)};
      floatx2 r3l = {rcp_native(e3l.x), rcp_native(e3l.y)};
      floatx2 r3h = {rcp_native(e3h.x), rcp_native(e3h.y)};
      a0l = fma2(vv, r0l, a0l);  a0h = fma2(vv, r0h, a0h);
      a1l = fma2(vv, r1l, a1l);  a1h = fma2(vv, r1h, a1h);
      a2l = fma2(vv, r2l, a2l);  a2h = fma2(vv, r2h, a2h);
      a3l = fma2(vv, r3l, a3l);  a3h = fma2(vv, r3h, a3h);
    }
  }
  const float sv = svas;
  float* pout = partials + (size_t)ch * (NB * S * S);
  float4 o0 = {a0l.x + sv, a0l.y + sv, a0h.x + sv, a0h.y + sv};
  float4 o1 = {a1l.x + sv, a1l.y + sv, a1h.x + sv, a1h.y + sv};
  float4 o2 = {a2l.x + sv, a2l.y + sv, a2h.x + sv, a2h.y + sv};
  float4 o3 = {a3l.x + sv, a3l.y + sv, a3h.x + sv, a3h.y + sv};
  *(float4*)&pout[(b * S + a0 + aa + 0) * S + c0 + ca] = o0;
  *(float4*)&pout[(b * S + a0 + aa + 1) * S + c0 + ca] = o1;
  *(float4*)&pout[(b * S + a0 + aa + 2) * S + c0 + ca] = o2;
  *(float4*)&pout[(b * S + a0 + aa + 3) * S + c0 + ca] = o3;
}

// ---------------------------------------------------------------------------
// Stage 3 (256 threads): combine of 8 partials parallel across all 4 waves;
// wave 0 re-reads the fp32 values from LDS (bit-exact) for top-4; each wave
// then computes one candidate's type logits.
__global__ __launch_bounds__(256) void topk_final(
    const float* __restrict__ partials, const __bf16* __restrict__ dpb,
    const __bf16* __restrict__ hpb, const float* __restrict__ fc_w,
    const float* __restrict__ fc_b, float* __restrict__ logits,
    float* __restrict__ out_type) {
  __shared__ int scand[TOPK];
  __shared__ float vsh[4][64];
  const int row = blockIdx.x;  // b*S + a
  const int t = threadIdx.x;
  const int wave = t >> 6, lane = t & 63;
  const int P = NB * S * S;
  {
    const int j = wave;
    const int c = row * S + j * 64 + lane;
    float s0 = partials[c]         + partials[c + P];
    float s1 = partials[c + 2 * P] + partials[c + 3 * P];
    float s2 = partials[c + 4 * P] + partials[c + 5 * P];
    float s3 = partials[c + 6 * P] + partials[c + 7 * P];
    float v = (s0 + s1) + (s2 + s3);
    logits[c] = v;
    vsh[j][lane] = v;
  }
  __syncthreads();
  if (wave == 0) {
    float v[4];
#pragma unroll
    for (int j = 0; j < 4; ++j) v[j] = vsh[j][lane];
#pragma unroll
    for (int k = 0; k < TOPK; ++k) {
      float bestv = v[0];
      int besti = lane;
#pragma unroll
      for (int j = 1; j < 4; ++j) {
        int c = j * 64 + lane;
        if (v[j] > bestv) { bestv = v[j]; besti = c; }
      }
#pragma unroll
      for (int off = 32; off > 0; off >>= 1) {
        float ov = __shfl_xor(bestv, off);
        int oi = __shfl_xor(besti, off);
        if (ov > bestv || (ov == bestv && oi < besti)) { bestv = ov; besti = oi; }
      }
      int mj = besti >> 6, ml = besti & 63;
#pragma unroll
      for (int j = 0; j < 4; ++j)
        if (lane == ml && j == mj) v[j] = -3.402823466e38f;
      if (lane == 0) scand[k] = besti;
    }
  }
  __syncthreads();
  const int k = wave;
  const __bf16* dp = dpb + (size_t)row * H;
  const int brow0 = (row >> 8) << 8;  // b*S
  const __bf16* hp = hpb + (size_t)(brow0 + scand[k]) * H;
  float acc[L] = {};
#pragma unroll
  for (int j = 0; j < 3; ++j) {
    const int o = j * 256 + lane * 4;
    bf16x4 dv = *(const bf16x4*)&dp[o];
    bf16x4 hv = *(const bf16x4*)&hp[o];
    float hd[4];
#pragma unroll
    for (int c = 0; c < 4; ++c)
      hd[c] = fast_tanh((float)dv[c] + (float)hv[c]);
#pragma unroll
    for (int l = 0; l < L; ++l) {
      float4 w = *(const float4*)&fc_w[l * H + o];
      acc[l] = fmaf(hd[0], w.x, acc[l]);
      acc[l] = fmaf(hd[1], w.y, acc[l]);
      acc[l] = fmaf(hd[2], w.z, acc[l]);
      acc[l] = fmaf(hd[3], w.w, acc[l]);
    }
  }
#pragma unroll
  for (int l = 0; l < L; ++l)
#pragma unroll
    for (int off = 32; off > 0; off >>= 1) acc[l] += __shfl_xor(acc[l], off);
  if (lane == 0) {
#pragma unroll
    for (int l = 0; l < L; ++l)
      out_type[((size_t)row * TOPK + k) * L + l] = acc[l] + fc_b[l];
  }
}

// ---------------------------------------------------------------------------
extern "C" void kernel_launch(void* const* d_in, const int* in_sizes, int n_in,
                              void* d_out, int out_size, void* d_ws, size_t ws_size,
                              hipStream_t stream) {
  const float* pooled  = (const float*)d_in[0];
  const float* Wa_w    = (const float*)d_in[1];
  const float* Wa_b    = (const float*)d_in[2];
  const float* Ua_w    = (const float*)d_in[3];
  const float* Ua_b    = (const float*)d_in[4];
  const float* va_w    = (const float*)d_in[5];
  const float* dense_w = (const float*)d_in[6];
  const float* dense_b = (const float*)d_in[7];
  const float* fc_w    = (const float*)d_in[8];
  const float* fc_b    = (const float*)d_in[9];

  float* logits   = (float*)d_out;            // (4,256,256)
  float* out_type = logits + NB * S * S;      // (4,256,4,4)

  // ws layout, ~27 MB. tobf16 writes Ah..Dh; mega reads them (gload_lds,
  // col-swizzled source), writes hijT (= exp2 of scaled proj) / dpb / hpb;
  // biaffine reads hijT, writes partials; topk reads partials/dpb/hpb.
  float*  hijT     = (float*)d_ws;                   // 1536 x 1024 f (6 MB)
  float*  partials = hijT + 1572864;                 // 2097152 f (8 MB)
  __bf16* dpb      = (__bf16*)(partials + 2097152);  // 786432 bf16
  __bf16* hpb      = dpb + 786432;                   // 786432 bf16
  __bf16* Ah       = hpb + 786432;                   // 786432 bf16 (1.5 MB)
  __bf16* Al       = Ah + 786432;                    // 786432 bf16
  __bf16* Bh       = Al + 786432;                    // 1179648 bf16 (2.25 MB)
  __bf16* Bl       = Bh + 1179648;                   // 1179648 bf16
  __bf16* Dh       = Bl + 1179648;                   // 1179648 bf16

  tobf16<<<dim3(1536), 256, 0, stream>>>(pooled, Wa_w, Ua_w, dense_w,
                                         Ah, Al, Bh, Bl, Dh);
  mega_mfma<<<dim3(16, 48), 256, 0, stream>>>(Ah, Al, Bh, Bl, Dh,
                                              Wa_b, Ua_b, dense_b,
                                              hijT, dpb, hpb);
  biaffine4<<<dim3(4, 4, NB * NH), 256, 0, stream>>>(hijT, va_w, partials);
  topk_final<<<dim3(1024), 256, 0, stream>>>(partials, dpb, hpb, fc_w, fc_b,
                                             logits, out_type);
}